// Round 6
// baseline (291.326 us; speedup 1.0000x reference)
//
#include <hip/hip_runtime.h>
#include <hip/hip_bf16.h>

// Problem constants
#define NTOK 32768
#define CH   256
#define NEXP 16

typedef __attribute__((ext_vector_type(8)))  short short8;   // 8 x bf16 (4 VGPR)
typedef __attribute__((ext_vector_type(16))) float f32x16;   // MFMA 32x32 accumulator

#define MFMA32(a, b, c) __builtin_amdgcn_mfma_f32_32x32x16_bf16((a), (b), (c), 0, 0, 0)
#define BC8(v) __builtin_bit_cast(short8, (v))

// fp32 -> bf16 round-to-nearest-even
static __device__ __forceinline__ unsigned short f2bf(float f) {
  unsigned int u = __builtin_bit_cast(unsigned int, f);
  unsigned int r = (u + 0x7fffu + ((u >> 16) & 1u)) >> 16;
  return (unsigned short)r;
}

// ---------------------------------------------------------------------------
// Workspace layout (bytes):
//   [0,       2228224)  W_packed  17*C*C bf16, MFMA B-fragment order
//   [2228224, 2244608)  gwt       gate_W transposed fp32 [e][c]
//   [2244608, 2310144)  frac_part 512*32 fp32
// (apack / combine are GONE — R6 fuses gating into the GEMM kernel.)
// ---------------------------------------------------------------------------

// Kernel 1: wpack (blocks 0..543) + transposed gate_W (block 544).
//   wpack line (e, db, kb, lane) holds B[k = kb*16 + (lane>>5)*8 + j][d = db*32 + (lane&31)]
__global__ __launch_bounds__(256) void wconvert_kernel(
    const float* __restrict__ share_W, const float* __restrict__ expert_W,
    const float* __restrict__ gate_W, uint4* __restrict__ wp,
    float* __restrict__ gwt) {
  if (blockIdx.x == 544) {   // gwt[e*256 + c] = gate_W[c*16 + e]
    int t = threadIdx.x;
#pragma unroll
    for (int i = 0; i < 16; i++) {
      int idx = i * 256 + t;
      gwt[(idx & 15) * 256 + (idx >> 4)] = gate_W[idx];
    }
    return;
  }
  int g = blockIdx.x * 256 + threadIdx.x;   // 17*8192 lines
  int e = g >> 13;
  int r = g & 8191;
  int lane = r & 63;
  int kb = (r >> 6) & 15;
  int db = r >> 10;
  int d  = db * 32 + (lane & 31);
  int k0 = kb * 16 + ((lane >> 5) << 3);
  const float* src = (e < 16) ? (expert_W + (size_t)e * 65536) : share_W;
  unsigned int p[4];
#pragma unroll
  for (int j = 0; j < 4; j++) {
    float f0 = src[(size_t)(k0 + 2 * j) * 256 + d];
    float f1 = src[(size_t)(k0 + 2 * j + 1) * 256 + d];
    p[j] = (unsigned int)f2bf(f0) | ((unsigned int)f2bf(f1) << 16);
  }
  wp[g] = make_uint4(p[0], p[1], p[2], p[3]);
}

// ---- fused-kernel GEMM helper: one K-quarter, 8 MFMA, A from swizzled LDS,
// B from registers. A-frag (kb, mi): uint4 index mi*1024 + r5*32 + ((kb*2+hi)^r5)
// (row-major [64][32] uint4 with slot s = j ^ (row&31) — all 32 lanes hit
// distinct slots => conflict-light). `first` folds zero-C init.
static __device__ __forceinline__ void slot_mfma4(
    f32x16 (&tacc)[2], const f32x16& zc, const uint4* __restrict__ at,
    const uint4 (&breg)[4], int q, int r5, int hi, bool first) {
  __builtin_amdgcn_s_setprio(1);
#pragma unroll
  for (int kbl = 0; kbl < 4; kbl++) {
    int kb = q * 4 + kbl;
    int ai = r5 * 32 + ((kb * 2 + hi) ^ r5);
    short8 a0 = BC8(at[ai]);
    short8 a1 = BC8(at[1024 + ai]);
    short8 bb = BC8(breg[kbl]);
    if (first && kbl == 0) {
      tacc[0] = MFMA32(a0, bb, zc);
      tacc[1] = MFMA32(a1, bb, zc);
    } else {
      tacc[0] = MFMA32(a0, bb, tacc[0]);
      tacc[1] = MFMA32(a1, bb, tacc[1]);
    }
  }
  __builtin_amdgcn_s_setprio(0);
}

// Kernel 2 (R6): FUSED gating + MoE GEMM. 512 blocks x 64 tokens, 512 thr
// (8 waves), 2 blocks/CU (4 waves/SIMD — v6 at 1 block/CU was
// serialization-bound: per-slot MFMA 1033 + VALU 450 + B-L1 1000 cyc summed
// instead of overlapped). Phases per block:
//   1. A-stage: inputs fp32 -> bf16 -> xor-swizzled row-major LDS (32 KB).
//   2. gating (R3 math, 8 tok/wave): LN + logits (gwt from L1-resident
//      global) + softmax + dyn-top-k; combine -> LDS wtile (no global
//      round-trip); frac partials -> frac_part.
//   3. v6 barrier-free GEMM: B global->VGPR double-buffered, e-outer/q-inner,
//      scale-add once per expert. One wave owns one 32-col block (dbp=w).
// Kills: gate_kernel launch, apack 16.7MB write + 16.7MB read, combine 2MB x2.
__global__ __launch_bounds__(512, 4) void moe_fused_kernel(
    const float* __restrict__ inputs, const float* __restrict__ conv_out,
    const float* __restrict__ domain_emb, const float* __restrict__ gwt,
    const float* __restrict__ gate_b, const float* __restrict__ ln_gamma,
    const float* __restrict__ ln_beta, const uint4* __restrict__ wpack,
    const float* __restrict__ expert_b, const float* __restrict__ share_b,
    float* __restrict__ out, float* __restrict__ frac_part) {
  extern __shared__ __align__(16) char smem[];
  uint4* at    = (uint4*)smem;             // [64 rows][32 slots] uint4 = 32 KB
  float* wtile = (float*)(smem + 32768);   // [e][tok] 16*64 fp32 = 4 KB
  float* route = (float*)(smem + 36864);   // [8][256] fp32 = 8 KB; fred alias

  int t = threadIdx.x, b = blockIdx.x;
  int w = t >> 6, l = t & 63;
  int dbp = w;                // wave -> cols dbp*32..+31
  int r5 = l & 31, hi = l >> 5;

  // ---- phase 1: A-stage (64 rows x 32 col-groups, 4 iters x 512 thr) ----
#pragma unroll
  for (int i = 0; i < 4; i++) {
    int idx = i * 512 + t;
    int r = idx >> 5, j = idx & 31;
    const float4* src = (const float4*)(inputs + ((size_t)b * 64 + r) * 256 + j * 8);
    float4 f0 = src[0], f1 = src[1];
    unsigned int p0 = (unsigned int)f2bf(f0.x) | ((unsigned int)f2bf(f0.y) << 16);
    unsigned int p1 = (unsigned int)f2bf(f0.z) | ((unsigned int)f2bf(f0.w) << 16);
    unsigned int p2 = (unsigned int)f2bf(f1.x) | ((unsigned int)f2bf(f1.y) << 16);
    unsigned int p3 = (unsigned int)f2bf(f1.z) | ((unsigned int)f2bf(f1.w) << 16);
    at[r * 32 + (j ^ (r & 31))] = make_uint4(p0, p1, p2, p3);
  }

  // early B prefetch for (e=0, q=0) — in flight across the gating phase
  const uint4* wb = wpack + (size_t)dbp * 1024 + l;
  uint4 bregA[4], bregB[4];
#pragma unroll
  for (int kbl = 0; kbl < 4; kbl++) bregA[kbl] = wb[kbl * 64];

  // ---- phase 2: gating, 8 tokens per wave (R3 gate math verbatim) ----
  {
    int lc = l * 4;
    float4 g4 = *(const float4*)(ln_gamma + lc);
    float4 be4 = *(const float4*)(ln_beta + lc);
    float4 de4 = *(const float4*)(domain_emb + lc);
    int e = l & 15, q = l >> 4;
    float gb = gate_b[e];
    const float4* gv4 = (const float4*)(gwt + e * 256 + q * 64);  // L1-hot
    float psel = 0.f, pw = 0.f;

    int n0 = b * 64 + w * 8;
    float4 x = *(const float4*)(conv_out + (size_t)n0 * 256 + lc);
    for (int i = 0; i < 8; i++) {
      float4 xn = *(const float4*)(conv_out + (size_t)(n0 + ((i + 1) & 7)) * 256 + lc);

      float s1 = x.x + x.y + x.z + x.w;
#pragma unroll
      for (int off = 1; off < 64; off <<= 1) s1 += __shfl_xor(s1, off);
      float mu = s1 * (1.f / 256.f);
      float dx = x.x - mu, dy = x.y - mu, dz = x.z - mu, dw = x.w - mu;
      float s2 = dx * dx + dy * dy + dz * dz + dw * dw;
#pragma unroll
      for (int off = 1; off < 64; off <<= 1) s2 += __shfl_xor(s2, off);
      float rstd = rsqrtf(s2 * (1.f / 256.f) + 1e-5f);
      float4 r;
      r.x = dx * rstd * g4.x + be4.x + de4.x;
      r.y = dy * rstd * g4.y + be4.y + de4.y;
      r.z = dz * rstd * g4.z + be4.z + de4.z;
      r.w = dw * rstd * g4.w + be4.w + de4.w;
      *(float4*)(&route[w * 256 + lc]) = r;
      asm volatile("s_waitcnt lgkmcnt(0)" ::: "memory");  // wave-private row
      __builtin_amdgcn_wave_barrier();

      float a0 = 0.f, a1 = 0.f, a2 = 0.f, a3 = 0.f;
#pragma unroll
      for (int ii = 0; ii < 16; ii += 4) {
        float4 r0 = *(const float4*)(&route[w * 256 + q * 64 + (ii + 0) * 4]);
        float4 r1 = *(const float4*)(&route[w * 256 + q * 64 + (ii + 1) * 4]);
        float4 r2 = *(const float4*)(&route[w * 256 + q * 64 + (ii + 2) * 4]);
        float4 r3 = *(const float4*)(&route[w * 256 + q * 64 + (ii + 3) * 4]);
        float4 g0 = gv4[ii + 0], g1 = gv4[ii + 1], g2 = gv4[ii + 2], g3 = gv4[ii + 3];
        a0 += r0.x * g0.x + r0.y * g0.y + r0.z * g0.z + r0.w * g0.w;
        a1 += r1.x * g1.x + r1.y * g1.y + r1.z * g1.z + r1.w * g1.w;
        a2 += r2.x * g2.x + r2.y * g2.y + r2.z * g2.z + r2.w * g2.w;
        a3 += r3.x * g3.x + r3.y * g3.y + r3.z * g3.z + r3.w * g3.w;
      }
      float acc = (a0 + a1) + (a2 + a3);
      acc += __shfl_xor(acc, 16);
      acc += __shfl_xor(acc, 32);
      float logit = acc + gb;

      float m = logit;
#pragma unroll
      for (int off = 1; off < 16; off <<= 1) m = fmaxf(m, __shfl_xor(m, off));
      float p = expf(logit - m);
      float sum = p;
#pragma unroll
      for (int off = 1; off < 16; off <<= 1) sum += __shfl_xor(sum, off);
      float wv = p / sum;

      float et = -wv * logf(wv + 1e-12f);
      float ent = et;
#pragma unroll
      for (int off = 1; off < 16; off <<= 1) ent += __shfl_xor(ent, off);
      float kf = ceilf(1.f + ent * (15.f / 2.7725887f));
      int k = (int)kf;
      k = max(1, min(16, k));

      int base = l & 48;
      int rank = 0;
#pragma unroll
      for (int j = 0; j < 16; j++) {
        float wj = __shfl(wv, base + j);
        rank += (wj > wv) || (wj == wv && j < e);
      }
      int sel = rank < k;
      float cmb = sel ? wv : 0.f;
      if (l < 16) wtile[e * 64 + (w * 8 + i)] = cmb;   // combine stays in LDS
      psel += (float)sel;
      pw += wv;

      x = xn;
    }

    // frac partials: route buffer is dead after this barrier -> reuse as fred
    __syncthreads();   // also makes atile + wtile visible for phase 3
    if (l < 16) {
      route[0 * 128 + w * 16 + l] = psel;
      route[1 * 128 + w * 16 + l] = pw;
    }
    __syncthreads();
    if (t < 32) {
      int kind = t >> 4, ee = t & 15;
      float v = 0.f;
#pragma unroll
      for (int ww = 0; ww < 8; ww++) v += route[kind * 128 + ww * 16 + ee];
      frac_part[b * 32 + t] = v;
    }
  }

  // ---- phase 3: GEMM (v6 structure, 1 col-block/wave) ----
  f32x16 facc[2];
#pragma unroll
  for (int mi = 0; mi < 2; mi++)
#pragma unroll
    for (int r = 0; r < 16; r++) facc[mi][r] = 0.f;
  f32x16 zc;
#pragma unroll
  for (int r = 0; r < 16; r++) zc[r] = 0.f;
  f32x16 tacc[2];
  int rowoff = hi * 4;   // C/D layout row offset

  for (int e = 0; e < 17; e++) {
    const uint4* we = wb + (size_t)e * 8192;
#pragma unroll
    for (int kbl = 0; kbl < 4; kbl++) bregB[kbl] = we[(4 + kbl) * 64];
    slot_mfma4(tacc, zc, at, bregA, 0, r5, hi, true);
#pragma unroll
    for (int kbl = 0; kbl < 4; kbl++) bregA[kbl] = we[(8 + kbl) * 64];
    slot_mfma4(tacc, zc, at, bregB, 1, r5, hi, false);
#pragma unroll
    for (int kbl = 0; kbl < 4; kbl++) bregB[kbl] = we[(12 + kbl) * 64];
    slot_mfma4(tacc, zc, at, bregA, 2, r5, hi, false);
    if (e < 16) {
#pragma unroll
      for (int kbl = 0; kbl < 4; kbl++) bregA[kbl] = we[8192 + kbl * 64];
    }
    slot_mfma4(tacc, zc, at, bregB, 3, r5, hi, false);

    // scale-add full-K expert output (once per expert)
    if (e < 16) {
#pragma unroll
      for (int mi = 0; mi < 2; mi++)
#pragma unroll
        for (int rg = 0; rg < 4; rg++) {
          float4 w4 = *(const float4*)&wtile[e * 64 + mi * 32 + 8 * rg + rowoff];
          float wj[4] = {w4.x, w4.y, w4.z, w4.w};
#pragma unroll
          for (int j = 0; j < 4; j++)
            facc[mi][rg * 4 + j] += wj[j] * tacc[mi][rg * 4 + j];
        }
    } else {  // shared expert, weight 1.0
#pragma unroll
      for (int mi = 0; mi < 2; mi++)
#pragma unroll
        for (int r = 0; r < 16; r++) facc[mi][r] += tacc[mi][r];
    }
  }

  // ---- epilogue: bias terms + store ----
  int col = dbp * 32 + r5;
  float sb = share_b[col];
  float eb[16];
#pragma unroll
  for (int e2 = 0; e2 < 16; e2++) eb[e2] = expert_b[e2 * 256 + col];
#pragma unroll
  for (int e2 = 0; e2 < 16; e2++)
#pragma unroll
    for (int mi = 0; mi < 2; mi++)
#pragma unroll
      for (int rg = 0; rg < 4; rg++) {
        float4 w4 = *(const float4*)&wtile[e2 * 64 + mi * 32 + 8 * rg + rowoff];
        float wj[4] = {w4.x, w4.y, w4.z, w4.w};
#pragma unroll
        for (int j = 0; j < 4; j++)
          facc[mi][rg * 4 + j] += wj[j] * eb[e2];
      }
#pragma unroll
  for (int mi = 0; mi < 2; mi++)
#pragma unroll
    for (int r = 0; r < 16; r++) {
      int row = mi * 32 + (r & 3) + ((r >> 2) << 3) + rowoff;
      out[((size_t)b * 64 + row) * 256 + col] = facc[mi][r] + sb;
    }
}

// Kernel 3: reduce balance-loss partials -> scalar at d_out[N*C]
__global__ __launch_bounds__(256) void finalize_kernel(
    const float* __restrict__ frac_part, float* __restrict__ loss_out) {
  __shared__ float acc[8][32];
  int t = threadIdx.x;
  int col = t & 31, seg = t >> 5;
  float s = 0.f;
  for (int i = seg; i < 512; i += 8) s += frac_part[i * 32 + col];
  acc[seg][col] = s;
  __syncthreads();
  if (t < 32) {
    float v = 0.f;
#pragma unroll
    for (int sg = 0; sg < 8; sg++) v += acc[sg][t];
    acc[0][t] = v;
  }
  __syncthreads();
  if (t == 0) {
    float loss = 0.f;
    for (int e = 0; e < 16; e++) {
      float ft = acc[0][e] * (1.f / 32768.f);
      float fp = acc[0][16 + e] * (1.f / 32768.f);
      loss += ft * fp;
    }
    loss_out[0] = loss * 16.f;
  }
}

extern "C" void kernel_launch(void* const* d_in, const int* in_sizes, int n_in,
                              void* d_out, int out_size, void* d_ws, size_t ws_size,
                              hipStream_t stream) {
  const float* inputs   = (const float*)d_in[0];
  const float* conv_out = (const float*)d_in[1];
  const float* demb     = (const float*)d_in[2];
  const float* share_W  = (const float*)d_in[3];
  const float* share_b  = (const float*)d_in[4];
  const float* gate_W   = (const float*)d_in[5];
  const float* gate_b   = (const float*)d_in[6];
  const float* expert_W = (const float*)d_in[7];
  const float* expert_b = (const float*)d_in[8];
  const float* ln_g     = (const float*)d_in[9];
  const float* ln_b     = (const float*)d_in[10];
  float* out = (float*)d_out;
  char* ws = (char*)d_ws;

  uint4* wpack = (uint4*)(ws);
  float* gwt   = (float*)(ws + 2228224);
  float* frac  = (float*)(ws + 2244608);

  // allow 44 KB dynamic LDS (idempotent; not a stream op, safe under capture)
  hipFuncSetAttribute((const void*)moe_fused_kernel,
                      hipFuncAttributeMaxDynamicSharedMemorySize, 45056);

  wconvert_kernel<<<dim3(545), dim3(256), 0, stream>>>(share_W, expert_W, gate_W,
                                                       wpack, gwt);
  moe_fused_kernel<<<dim3(512), dim3(512), 45056, stream>>>(
      inputs, conv_out, demb, gwt, gate_b, ln_g, ln_b, wpack,
      expert_b, share_b, out, frac);
  finalize_kernel<<<dim3(1), dim3(256), 0, stream>>>(frac, out + 8388608);
}

// Round 8
// 241.230 us; speedup vs baseline: 1.2077x; 1.2077x over previous
//
#include <hip/hip_runtime.h>
#include <hip/hip_bf16.h>

// Problem constants
#define NTOK 32768
#define CH   256
#define NEXP 16

typedef __attribute__((ext_vector_type(8)))  short short8;   // 8 x bf16 (4 VGPR)
typedef __attribute__((ext_vector_type(16))) float f32x16;   // MFMA 32x32 accumulator

#define MFMA32(a, b, c) __builtin_amdgcn_mfma_f32_32x32x16_bf16((a), (b), (c), 0, 0, 0)
#define BC8(v) __builtin_bit_cast(short8, (v))

// fp32 -> bf16 round-to-nearest-even
static __device__ __forceinline__ unsigned short f2bf(float f) {
  unsigned int u = __builtin_bit_cast(unsigned int, f);
  unsigned int r = (u + 0x7fffu + ((u >> 16) & 1u)) >> 16;
  return (unsigned short)r;
}

// ---------------------------------------------------------------------------
// Workspace layout (bytes):
//   [0,       2228224)  W_packed  17*C*C bf16, MFMA B-fragment order
//   [2228224, 2244608)  gwt       gate_W transposed fp32 [e][c]
//   [2244608, 4341760)  combine   N*16 fp32
//   [4341760, 4407296)  frac_part 512*32 fp32
// (apack is GONE — the GEMM stages A itself from inputs.)
// ---------------------------------------------------------------------------

// Kernel 1: wpack (blocks 0..543) + transposed gate_W (block 544).
//   wpack line (e, db, kb, lane) holds B[k = kb*16 + (lane>>5)*8 + j][d = db*32 + (lane&31)]
__global__ __launch_bounds__(256) void wconvert_kernel(
    const float* __restrict__ share_W, const float* __restrict__ expert_W,
    const float* __restrict__ gate_W, uint4* __restrict__ wp,
    float* __restrict__ gwt) {
  if (blockIdx.x == 544) {   // gwt[e*256 + c] = gate_W[c*16 + e]
    int t = threadIdx.x;
#pragma unroll
    for (int i = 0; i < 16; i++) {
      int idx = i * 256 + t;
      gwt[(idx & 15) * 256 + (idx >> 4)] = gate_W[idx];
    }
    return;
  }
  int g = blockIdx.x * 256 + threadIdx.x;   // 17*8192 lines
  int e = g >> 13;
  int r = g & 8191;
  int lane = r & 63;
  int kb = (r >> 6) & 15;
  int db = r >> 10;
  int d  = db * 32 + (lane & 31);
  int k0 = kb * 16 + ((lane >> 5) << 3);
  const float* src = (e < 16) ? (expert_W + (size_t)e * 65536) : share_W;
  unsigned int p[4];
#pragma unroll
  for (int j = 0; j < 4; j++) {
    float f0 = src[(size_t)(k0 + 2 * j) * 256 + d];
    float f1 = src[(size_t)(k0 + 2 * j + 1) * 256 + d];
    p[j] = (unsigned int)f2bf(f0) | ((unsigned int)f2bf(f1) << 16);
  }
  wp[g] = make_uint4(p[0], p[1], p[2], p[3]);
}

// Kernel 2 (R7 resubmission): SLIM gate — pure gating, no A-staging (moved
// to GEMM), no apack, no atile, no gwT LDS (gate weights from L1-cached
// transposed gwt). 512 blocks x 64 tok, 8 waves x 8 tok/wave. LDS 9.2 KB.
__global__ __launch_bounds__(512, 2) void gate_kernel(
    const float* __restrict__ conv_out, const float* __restrict__ domain_emb,
    const float* __restrict__ gwt, const float* __restrict__ gate_b,
    const float* __restrict__ ln_gamma, const float* __restrict__ ln_beta,
    float* __restrict__ combine, float* __restrict__ frac_part) {
  __shared__ float route[8][256];    // per-wave private rows
  __shared__ float fred[2][8][16];
  int t = threadIdx.x, b = blockIdx.x;
  int w = t >> 6, l = t & 63;

  int lc = l * 4;
  float4 g4 = *(const float4*)(ln_gamma + lc);
  float4 be4 = *(const float4*)(ln_beta + lc);
  float4 de4 = *(const float4*)(domain_emb + lc);
  int e = l & 15, q = l >> 4;
  float gb = gate_b[e];

  // gate-weight quarter straight from global (16 KB, L1/L2-hot, broadcast)
  float4 gwreg[16];
  const float4* gv4 = (const float4*)(gwt + e * 256 + q * 64);
#pragma unroll
  for (int ii = 0; ii < 16; ii++) gwreg[ii] = gv4[ii];

  float psel = 0.f, pw = 0.f;
  int n0 = b * 64 + w * 8;
  float4 x = *(const float4*)(conv_out + (size_t)n0 * 256 + lc);
  for (int i = 0; i < 8; i++) {
    // prefetch next token's row (wraps at i==7; value unused)
    float4 xn = *(const float4*)(conv_out + (size_t)(n0 + ((i + 1) & 7)) * 256 + lc);

    float s1 = x.x + x.y + x.z + x.w;
#pragma unroll
    for (int off = 1; off < 64; off <<= 1) s1 += __shfl_xor(s1, off);
    float mu = s1 * (1.f / 256.f);
    float dx = x.x - mu, dy = x.y - mu, dz = x.z - mu, dw = x.w - mu;
    float s2 = dx * dx + dy * dy + dz * dz + dw * dw;
#pragma unroll
    for (int off = 1; off < 64; off <<= 1) s2 += __shfl_xor(s2, off);
    float rstd = rsqrtf(s2 * (1.f / 256.f) + 1e-5f);
    float4 r;
    r.x = dx * rstd * g4.x + be4.x + de4.x;
    r.y = dy * rstd * g4.y + be4.y + de4.y;
    r.z = dz * rstd * g4.z + be4.z + de4.z;
    r.w = dw * rstd * g4.w + be4.w + de4.w;
    *(float4*)(&route[w][lc]) = r;
    // route[w] is wave-private: wave-local fence instead of block barrier
    asm volatile("s_waitcnt lgkmcnt(0)" ::: "memory");
    __builtin_amdgcn_wave_barrier();

    // logit: lane (q,e) dots channels [q*64, q*64+64) against reg-resident gw
    float a0 = 0.f, a1 = 0.f, a2 = 0.f, a3 = 0.f;
#pragma unroll
    for (int ii = 0; ii < 16; ii += 4) {
      float4 r0 = *(const float4*)(&route[w][q * 64 + (ii + 0) * 4]);
      float4 r1 = *(const float4*)(&route[w][q * 64 + (ii + 1) * 4]);
      float4 r2 = *(const float4*)(&route[w][q * 64 + (ii + 2) * 4]);
      float4 r3 = *(const float4*)(&route[w][q * 64 + (ii + 3) * 4]);
      a0 += r0.x * gwreg[ii + 0].x + r0.y * gwreg[ii + 0].y + r0.z * gwreg[ii + 0].z + r0.w * gwreg[ii + 0].w;
      a1 += r1.x * gwreg[ii + 1].x + r1.y * gwreg[ii + 1].y + r1.z * gwreg[ii + 1].z + r1.w * gwreg[ii + 1].w;
      a2 += r2.x * gwreg[ii + 2].x + r2.y * gwreg[ii + 2].y + r2.z * gwreg[ii + 2].z + r2.w * gwreg[ii + 2].w;
      a3 += r3.x * gwreg[ii + 3].x + r3.y * gwreg[ii + 3].y + r3.z * gwreg[ii + 3].z + r3.w * gwreg[ii + 3].w;
    }
    float acc = (a0 + a1) + (a2 + a3);
    acc += __shfl_xor(acc, 16);
    acc += __shfl_xor(acc, 32);
    float logit = acc + gb;

    float m = logit;
#pragma unroll
    for (int off = 1; off < 16; off <<= 1) m = fmaxf(m, __shfl_xor(m, off));
    float p = expf(logit - m);
    float sum = p;
#pragma unroll
    for (int off = 1; off < 16; off <<= 1) sum += __shfl_xor(sum, off);
    float wv = p / sum;

    float et = -wv * logf(wv + 1e-12f);
    float ent = et;
#pragma unroll
    for (int off = 1; off < 16; off <<= 1) ent += __shfl_xor(ent, off);
    float kf = ceilf(1.f + ent * (15.f / 2.7725887f));
    int k = (int)kf;
    k = max(1, min(16, k));

    int base = l & 48;
    int rank = 0;
#pragma unroll
    for (int j = 0; j < 16; j++) {
      float wj = __shfl(wv, base + j);
      rank += (wj > wv) || (wj == wv && j < e);
    }
    int sel = rank < k;
    float cmb = sel ? wv : 0.f;
    int n = n0 + i;
    if (l < 16) combine[(size_t)n * 16 + e] = cmb;
    psel += (float)sel;
    pw += wv;

    x = xn;
  }

  if (l < 16) { fred[0][w][l] = psel; fred[1][w][l] = pw; }
  __syncthreads();
  if (t < 32) {
    int kind = t >> 4, ee = t & 15;
    float v = 0.f;
#pragma unroll
    for (int ww = 0; ww < 8; ww++) v += fred[kind][ww][ee];
    frac_part[b * 32 + t] = v;
  }
}

// ---- kernel 3 helpers (v7) ----
// B prefetch: unchanged from v6 (global->VGPR, coalesced 1KB lines, L1/L2).
static __device__ __forceinline__ void pref_b(
    uint4 (&breg)[8], const uint4* __restrict__ we, int q) {
#pragma unroll
  for (int f = 0; f < 8; f++) {
    int kbl = f >> 1, d = f & 1;
    breg[f] = we[(size_t)d * 1024 + (q * 4 + kbl) * 64];
  }
}

// one K-quarter slot: A from fragment-ordered LDS with kb-XOR swizzle.
// A uint4 index = kb*256 + mb*64 + hi*32 + (r5 ^ kb); per line the 64 lanes
// hit a permutation of 0..63 => conflict-pattern identical to v6's linear
// reads (which measured clean). abase = mbp*128 + hi*32.
static __device__ __forceinline__ void slot_mfma(
    f32x16 (&tacc)[2][2], const f32x16& zc, const uint4* __restrict__ at,
    const uint4 (&breg)[8], int q, int abase, int r5, bool first) {
  __builtin_amdgcn_s_setprio(1);
#pragma unroll
  for (int kbl = 0; kbl < 4; kbl++) {
    int kb = q * 4 + kbl;
    int ax = kb * 256 + abase + (r5 ^ kb);
    short8 a0 = BC8(at[ax]);
    short8 a1 = BC8(at[ax + 64]);
    short8 b0 = BC8(breg[kbl * 2 + 0]);
    short8 b1 = BC8(breg[kbl * 2 + 1]);
    if (first && kbl == 0) {
      tacc[0][0] = MFMA32(a0, b0, zc);
      tacc[0][1] = MFMA32(a0, b1, zc);
      tacc[1][0] = MFMA32(a1, b0, zc);
      tacc[1][1] = MFMA32(a1, b1, zc);
    } else {
      tacc[0][0] = MFMA32(a0, b0, tacc[0][0]);
      tacc[0][1] = MFMA32(a0, b1, tacc[0][1]);
      tacc[1][0] = MFMA32(a1, b0, tacc[1][0]);
      tacc[1][1] = MFMA32(a1, b1, tacc[1][1]);
    }
  }
  __builtin_amdgcn_s_setprio(0);
}

// Kernel 3 (v7): v6 GEMM (barrier-free main loop, B global->VGPR dbuf,
// e-outer/q-inner, scale-add once/expert) with ONE change: A is staged
// in-kernel from fp32 inputs (fragment order + kb-XOR row swizzle so the
// prologue ds_writes don't 16-way conflict). Kills the apack round-trip
// (33 MB) and gate's staging phases. R6's fusion lesson applied: keep
// 128-tok tiles (A-reuse) and fragment-ordered conflict-clean A reads.
__global__ __launch_bounds__(512, 2) void moe_gemm_kernel(
    const float* __restrict__ inputs, const uint4* __restrict__ wpack,
    const float* __restrict__ combine, const float* __restrict__ expert_b,
    const float* __restrict__ share_b, float* __restrict__ out) {
  extern __shared__ __align__(16) char smem[];
  uint4* at    = (uint4*)smem;              // 4096 uint4 = 64 KB fragment order
  float* wtile = (float*)(smem + 65536);    // [e][row] 16*128 fp32 = 8 KB

  int t = threadIdx.x, b = blockIdx.x;
  int w = t >> 6, l = t & 63;
  int mbp = w >> 2;      // 0..1 -> rows (mbp*2+{0,1})*32
  int dbp = w & 3;       // 0..3 -> cols (dbp*2+{0,1})*32
  int r5 = l & 31, hi = l >> 5;

  // ---- A-stage: inputs fp32 -> bf16 -> fragment-order LDS ----
  // (row, j) -> uint4 idx (j>>1)*256 + (row>>5)*64 + (j&1)*32 + ((row&31)^(j>>1))
#pragma unroll
  for (int i = 0; i < 8; i++) {
    int idx = i * 512 + t;
    int row = idx >> 5;          // 0..127
    int j = idx & 31;
    const float4* src = (const float4*)(inputs + ((size_t)b * 128 + row) * 256 + j * 8);
    float4 f0 = src[0], f1 = src[1];
    unsigned int p0 = (unsigned int)f2bf(f0.x) | ((unsigned int)f2bf(f0.y) << 16);
    unsigned int p1 = (unsigned int)f2bf(f0.z) | ((unsigned int)f2bf(f0.w) << 16);
    unsigned int p2 = (unsigned int)f2bf(f1.x) | ((unsigned int)f2bf(f1.y) << 16);
    unsigned int p3 = (unsigned int)f2bf(f1.z) | ((unsigned int)f2bf(f1.w) << 16);
    int kb = j >> 1, hib = j & 1;
    at[kb * 256 + (row >> 5) * 64 + hib * 32 + ((row & 31) ^ kb)] =
        make_uint4(p0, p1, p2, p3);
  }
  // wtile transposed stage: combine[tok][e] -> wtile[e*128 + tok]
  {
    const float* cg = combine + (size_t)b * 2048;
#pragma unroll
    for (int i = 0; i < 4; i++) {
      int idx = i * 512 + t;
      wtile[(idx & 15) * 128 + (idx >> 4)] = cg[idx];
    }
  }

  // early B prefetch for (e=0, q=0)
  const uint4* wb = wpack + (size_t)(dbp * 2) * 1024 + l;
  uint4 bregA[8], bregB[8];
  pref_b(bregA, wb, 0);

  __syncthreads();   // LDS staging visible to all waves

  f32x16 facc[2][2];
#pragma unroll
  for (int mi = 0; mi < 2; mi++)
#pragma unroll
    for (int d = 0; d < 2; d++)
#pragma unroll
      for (int r = 0; r < 16; r++) facc[mi][d][r] = 0.f;
  f32x16 zc;
#pragma unroll
  for (int r = 0; r < 16; r++) zc[r] = 0.f;

  f32x16 tacc[2][2];
  int rowoff = hi * 4;              // C/D layout row offset
  int abase = mbp * 128 + hi * 32;  // A-frag base for this wave-half

  for (int e = 0; e < 17; e++) {
    const uint4* we = wb + (size_t)e * 8192;
    pref_b(bregB, we, 1);
    slot_mfma(tacc, zc, at, bregA, 0, abase, r5, true);
    pref_b(bregA, we, 2);
    slot_mfma(tacc, zc, at, bregB, 1, abase, r5, false);
    pref_b(bregB, we, 3);
    slot_mfma(tacc, zc, at, bregA, 2, abase, r5, false);
    if (e < 16) pref_b(bregA, we + 8192, 0);
    slot_mfma(tacc, zc, at, bregB, 3, abase, r5, false);

    // scale-add full-K expert output: facc += w[row,e] * tacc (once per expert)
    if (e < 16) {
#pragma unroll
      for (int mi = 0; mi < 2; mi++)
#pragma unroll
        for (int rg = 0; rg < 4; rg++) {
          float4 w4 = *(const float4*)&wtile[e * 128 + (mbp * 2 + mi) * 32 + 8 * rg + rowoff];
          float wj[4] = {w4.x, w4.y, w4.z, w4.w};
#pragma unroll
          for (int j = 0; j < 4; j++) {
            facc[mi][0][rg * 4 + j] += wj[j] * tacc[mi][0][rg * 4 + j];
            facc[mi][1][rg * 4 + j] += wj[j] * tacc[mi][1][rg * 4 + j];
          }
        }
    } else {  // shared expert, weight 1.0
#pragma unroll
      for (int mi = 0; mi < 2; mi++)
#pragma unroll
        for (int r = 0; r < 16; r++) {
          facc[mi][0][r] += tacc[mi][0][r];
          facc[mi][1][r] += tacc[mi][1][r];
        }
    }
  }

  // ---- final epilogue: bias terms + store ----
  int col = r5;
  int cg0 = (dbp * 2 + 0) * 32 + col;
  int cg1 = (dbp * 2 + 1) * 32 + col;
  float sb0 = share_b[cg0], sb1 = share_b[cg1];
  float eb0[16], eb1[16];
#pragma unroll
  for (int e2 = 0; e2 < 16; e2++) {
    eb0[e2] = expert_b[e2 * 256 + cg0];
    eb1[e2] = expert_b[e2 * 256 + cg1];
  }
  // facc += sum_e w[row,e] * expert_b[e,col]
#pragma unroll
  for (int e2 = 0; e2 < 16; e2++)
#pragma unroll
    for (int mi = 0; mi < 2; mi++)
#pragma unroll
      for (int rg = 0; rg < 4; rg++) {
        float4 w4 = *(const float4*)&wtile[e2 * 128 + (mbp * 2 + mi) * 32 + 8 * rg + rowoff];
        float wj[4] = {w4.x, w4.y, w4.z, w4.w};
#pragma unroll
        for (int j = 0; j < 4; j++) {
          facc[mi][0][rg * 4 + j] += wj[j] * eb0[e2];
          facc[mi][1][rg * 4 + j] += wj[j] * eb1[e2];
        }
      }
#pragma unroll
  for (int mi = 0; mi < 2; mi++)
#pragma unroll
    for (int r = 0; r < 16; r++) {
      int row = (mbp * 2 + mi) * 32 + (r & 3) + ((r >> 2) << 3) + rowoff;
      size_t n = (size_t)b * 128 + row;
      out[n * 256 + cg0] = facc[mi][0][r] + sb0;
      out[n * 256 + cg1] = facc[mi][1][r] + sb1;
    }
}

// Kernel 4: reduce balance-loss partials -> scalar at d_out[N*C]
__global__ __launch_bounds__(256) void finalize_kernel(
    const float* __restrict__ frac_part, float* __restrict__ loss_out) {
  __shared__ float acc[8][32];
  int t = threadIdx.x;
  int col = t & 31, seg = t >> 5;
  float s = 0.f;
  for (int i = seg; i < 512; i += 8) s += frac_part[i * 32 + col];
  acc[seg][col] = s;
  __syncthreads();
  if (t < 32) {
    float v = 0.f;
#pragma unroll
    for (int sg = 0; sg < 8; sg++) v += acc[sg][t];
    acc[0][t] = v;
  }
  __syncthreads();
  if (t == 0) {
    float loss = 0.f;
    for (int e = 0; e < 16; e++) {
      float ft = acc[0][e] * (1.f / 32768.f);
      float fp = acc[0][16 + e] * (1.f / 32768.f);
      loss += ft * fp;
    }
    loss_out[0] = loss * 16.f;
  }
}

extern "C" void kernel_launch(void* const* d_in, const int* in_sizes, int n_in,
                              void* d_out, int out_size, void* d_ws, size_t ws_size,
                              hipStream_t stream) {
  const float* inputs   = (const float*)d_in[0];
  const float* conv_out = (const float*)d_in[1];
  const float* demb     = (const float*)d_in[2];
  const float* share_W  = (const float*)d_in[3];
  const float* share_b  = (const float*)d_in[4];
  const float* gate_W   = (const float*)d_in[5];
  const float* gate_b   = (const float*)d_in[6];
  const float* expert_W = (const float*)d_in[7];
  const float* expert_b = (const float*)d_in[8];
  const float* ln_g     = (const float*)d_in[9];
  const float* ln_b     = (const float*)d_in[10];
  float* out = (float*)d_out;
  char* ws = (char*)d_ws;

  uint4* wpack   = (uint4*)(ws);
  float* gwt     = (float*)(ws + 2228224);
  float* combine = (float*)(ws + 2244608);
  float* frac    = (float*)(ws + 4341760);

  // allow 72 KB dynamic LDS (idempotent; not a stream op, safe under capture)
  hipFuncSetAttribute((const void*)moe_gemm_kernel,
                      hipFuncAttributeMaxDynamicSharedMemorySize, 73728);

  wconvert_kernel<<<dim3(545), dim3(256), 0, stream>>>(share_W, expert_W, gate_W,
                                                       wpack, gwt);
  gate_kernel<<<dim3(512), dim3(512), 0, stream>>>(conv_out, demb, gwt, gate_b,
                                                   ln_g, ln_b, combine, frac);
  moe_gemm_kernel<<<dim3(256), dim3(512), 73728, stream>>>(inputs, wpack, combine,
                                                           expert_b, share_b, out);
  finalize_kernel<<<dim3(1), dim3(256), 0, stream>>>(frac, out + 8388608);
}

// Round 9
// 220.798 us; speedup vs baseline: 1.3194x; 1.0925x over previous
//
#include <hip/hip_runtime.h>
#include <hip/hip_bf16.h>

// Problem constants
#define NTOK 32768
#define CH   256
#define NEXP 16

typedef __attribute__((ext_vector_type(8)))  short short8;   // 8 x bf16 (4 VGPR)
typedef __attribute__((ext_vector_type(16))) float f32x16;   // MFMA 32x32 accumulator

#define MFMA32(a, b, c) __builtin_amdgcn_mfma_f32_32x32x16_bf16((a), (b), (c), 0, 0, 0)
#define BC8(v) __builtin_bit_cast(short8, (v))

// fp32 -> bf16 round-to-nearest-even
static __device__ __forceinline__ unsigned short f2bf(float f) {
  unsigned int u = __builtin_bit_cast(unsigned int, f);
  unsigned int r = (u + 0x7fffu + ((u >> 16) & 1u)) >> 16;
  return (unsigned short)r;
}

// ---------------------------------------------------------------------------
// Workspace layout (bytes):
//   [0,       2228224)  W_packed  17*C*C bf16, MFMA B-fragment order
//   [2228224, 4325376)  combine   N*16 fp32
//   [4325376, 4390912)  frac_part 512*32 fp32
// ---------------------------------------------------------------------------

// Kernel 1 (R9): FUSED prep = gate (blocks 0..511) + wconvert (blocks
// 512..783). Independent block-level jobs, one launch (saves a launch gap).
// Gate: R5-proven math, 8 waves x 8 tok, gwT staged to LDS. Wconvert:
// expert_W/share_W -> bf16 B-fragment order, 512 lines/block x 272 blocks.
__global__ __launch_bounds__(512, 2) void prep_kernel(
    const float* __restrict__ conv_out, const float* __restrict__ domain_emb,
    const float* __restrict__ gate_W, const float* __restrict__ gate_b,
    const float* __restrict__ ln_gamma, const float* __restrict__ ln_beta,
    const float* __restrict__ share_W, const float* __restrict__ expert_W,
    float* __restrict__ combine, float* __restrict__ frac_part,
    uint4* __restrict__ wp) {
  int t = threadIdx.x, b = blockIdx.x;

  if (b >= 512) {   // ---- wconvert branch ----
    int g = (b - 512) * 512 + t;   // 0..139263 (= 17*8192 exactly)
    int e = g >> 13;
    int r = g & 8191;
    int lane = r & 63;
    int kb = (r >> 6) & 15;
    int db = r >> 10;
    int d  = db * 32 + (lane & 31);
    int k0 = kb * 16 + ((lane >> 5) << 3);
    const float* src = (e < 16) ? (expert_W + (size_t)e * 65536) : share_W;
    unsigned int p[4];
#pragma unroll
    for (int j = 0; j < 4; j++) {
      float f0 = src[(size_t)(k0 + 2 * j) * 256 + d];
      float f1 = src[(size_t)(k0 + 2 * j + 1) * 256 + d];
      p[j] = (unsigned int)f2bf(f0) | ((unsigned int)f2bf(f1) << 16);
    }
    wp[g] = make_uint4(p[0], p[1], p[2], p[3]);
    return;
  }

  // ---- gate branch ----
  __shared__ float route[8][256];          // per-wave private rows
  __shared__ __align__(16) float gwT[16 * 260];  // [e][c], pad 260
  __shared__ float fred[2][8][16];
  int w = t >> 6, l = t & 63;

  // stage gate_W transposed: gwT[e*260 + c] = gate_W[c*16 + e]
#pragma unroll
  for (int i = 0; i < 8; i++) {
    int idx = i * 512 + t;
    gwT[(idx & 15) * 260 + (idx >> 4)] = gate_W[idx];
  }
  __syncthreads();

  int lc = l * 4;
  float4 g4 = *(const float4*)(ln_gamma + lc);
  float4 be4 = *(const float4*)(ln_beta + lc);
  float4 de4 = *(const float4*)(domain_emb + lc);
  int e = l & 15, q = l >> 4;
  float gb = gate_b[e];

  float4 gwreg[16];
#pragma unroll
  for (int ii = 0; ii < 16; ii++)
    gwreg[ii] = *(const float4*)&gwT[e * 260 + q * 64 + ii * 4];

  float psel = 0.f, pw = 0.f;
  int n0 = b * 64 + w * 8;
  float4 x = *(const float4*)(conv_out + (size_t)n0 * 256 + lc);
  for (int i = 0; i < 8; i++) {
    float4 xn = *(const float4*)(conv_out + (size_t)(n0 + ((i + 1) & 7)) * 256 + lc);

    float s1 = x.x + x.y + x.z + x.w;
#pragma unroll
    for (int off = 1; off < 64; off <<= 1) s1 += __shfl_xor(s1, off);
    float mu = s1 * (1.f / 256.f);
    float dx = x.x - mu, dy = x.y - mu, dz = x.z - mu, dw = x.w - mu;
    float s2 = dx * dx + dy * dy + dz * dz + dw * dw;
#pragma unroll
    for (int off = 1; off < 64; off <<= 1) s2 += __shfl_xor(s2, off);
    float rstd = rsqrtf(s2 * (1.f / 256.f) + 1e-5f);
    float4 r;
    r.x = dx * rstd * g4.x + be4.x + de4.x;
    r.y = dy * rstd * g4.y + be4.y + de4.y;
    r.z = dz * rstd * g4.z + be4.z + de4.z;
    r.w = dw * rstd * g4.w + be4.w + de4.w;
    *(float4*)(&route[w][lc]) = r;
    // route[w] is wave-private: wave-local fence instead of block barrier
    asm volatile("s_waitcnt lgkmcnt(0)" ::: "memory");
    __builtin_amdgcn_wave_barrier();

    float a0 = 0.f, a1 = 0.f, a2 = 0.f, a3 = 0.f;
#pragma unroll
    for (int ii = 0; ii < 16; ii += 4) {
      float4 r0 = *(const float4*)(&route[w][q * 64 + (ii + 0) * 4]);
      float4 r1 = *(const float4*)(&route[w][q * 64 + (ii + 1) * 4]);
      float4 r2 = *(const float4*)(&route[w][q * 64 + (ii + 2) * 4]);
      float4 r3 = *(const float4*)(&route[w][q * 64 + (ii + 3) * 4]);
      a0 += r0.x * gwreg[ii + 0].x + r0.y * gwreg[ii + 0].y + r0.z * gwreg[ii + 0].z + r0.w * gwreg[ii + 0].w;
      a1 += r1.x * gwreg[ii + 1].x + r1.y * gwreg[ii + 1].y + r1.z * gwreg[ii + 1].z + r1.w * gwreg[ii + 1].w;
      a2 += r2.x * gwreg[ii + 2].x + r2.y * gwreg[ii + 2].y + r2.z * gwreg[ii + 2].z + r2.w * gwreg[ii + 2].w;
      a3 += r3.x * gwreg[ii + 3].x + r3.y * gwreg[ii + 3].y + r3.z * gwreg[ii + 3].z + r3.w * gwreg[ii + 3].w;
    }
    float acc = (a0 + a1) + (a2 + a3);
    acc += __shfl_xor(acc, 16);
    acc += __shfl_xor(acc, 32);
    float logit = acc + gb;

    float m = logit;
#pragma unroll
    for (int off = 1; off < 16; off <<= 1) m = fmaxf(m, __shfl_xor(m, off));
    float p = expf(logit - m);
    float sum = p;
#pragma unroll
    for (int off = 1; off < 16; off <<= 1) sum += __shfl_xor(sum, off);
    float wv = p / sum;

    float et = -wv * logf(wv + 1e-12f);
    float ent = et;
#pragma unroll
    for (int off = 1; off < 16; off <<= 1) ent += __shfl_xor(ent, off);
    float kf = ceilf(1.f + ent * (15.f / 2.7725887f));
    int k = (int)kf;
    k = max(1, min(16, k));

    int base = l & 48;
    int rank = 0;
#pragma unroll
    for (int j = 0; j < 16; j++) {
      float wj = __shfl(wv, base + j);
      rank += (wj > wv) || (wj == wv && j < e);
    }
    int sel = rank < k;
    float cmb = sel ? wv : 0.f;
    int n = n0 + i;
    if (l < 16) combine[(size_t)n * 16 + e] = cmb;
    psel += (float)sel;
    pw += wv;

    x = xn;
  }

  if (l < 16) { fred[0][w][l] = psel; fred[1][w][l] = pw; }
  __syncthreads();
  if (t < 32) {
    int kind = t >> 4, ee = t & 15;
    float v = 0.f;
#pragma unroll
    for (int ww = 0; ww < 8; ww++) v += fred[kind][ww][ee];
    frac_part[b * 32 + t] = v;
  }
}

// ---- kernel 2 helpers (v8) ----
// B prefetch for (expert-ptr we, quarter q): 4 coalesced 1KB lines, L2-served.
static __device__ __forceinline__ void pref_b4(
    uint4 (&breg)[4], const uint4* __restrict__ we, int q) {
#pragma unroll
  for (int kbl = 0; kbl < 4; kbl++) breg[kbl] = we[(q * 4 + kbl) * 64];
}

// one K-quarter: 8 MFMA (2 m-blocks x 4 kbl), A from fragment-ordered LDS
// (kb-XOR swizzle, permutation-of-0..31 per line => conflict-clean), B from
// registers. tacc zero-initialized per expert by caller.
static __device__ __forceinline__ void slot_mfma4(
    f32x16 (&tacc)[2], const uint4* __restrict__ at, const uint4 (&breg)[4],
    int q, int hi, int r5) {
  __builtin_amdgcn_s_setprio(1);
#pragma unroll
  for (int kbl = 0; kbl < 4; kbl++) {
    int kb = q * 4 + kbl;
    int ax = kb * 128 + hi * 32 + (r5 ^ kb);
    short8 a0 = BC8(at[ax]);        // mb=0
    short8 a1 = BC8(at[ax + 64]);   // mb=1
    short8 bb = BC8(breg[kbl]);
    tacc[0] = MFMA32(a0, bb, tacc[0]);
    tacc[1] = MFMA32(a1, bb, tacc[1]);
  }
  __builtin_amdgcn_s_setprio(0);
}

// Kernel 2 (v8): R8 diagnosis — 2 waves/SIMD is TLP-starved (MFMA 1033 +
// VALU 413 of 2665 cyc/slot; rest = both-waves-stalled latency). Fix:
// 64-tok tiles, grid 512 = 2 blocks/CU = 4 waves/SIMD. Per-wave state cut
// to fit the 128-VGPR cap of (512,4): wave owns 2 m-blocks x 1 col-block
// (facc 32 + tacc 32 + breg 32 regs); zc eliminated (inline-0 tacc init).
// Graceful fallback: if VGPR > 128, 1 block/CU = R8 perf. Block 512 runs
// the balance-loss finalize (frac ready — prep kernel completed), saving
// the 4th launch.
__global__ __launch_bounds__(512, 4) void moe_gemm_kernel(
    const float* __restrict__ inputs, const uint4* __restrict__ wpack,
    const float* __restrict__ combine, const float* __restrict__ expert_b,
    const float* __restrict__ share_b, float* __restrict__ out,
    const float* __restrict__ frac_part) {
  extern __shared__ __align__(16) char smem[];
  int t = threadIdx.x, b = blockIdx.x;

  if (b == 512) {   // ---- finalize branch: balance loss -> out[N*C] ----
    float* acc = (float*)smem;   // [16][32]
    int col = t & 31, seg = t >> 5;   // seg 0..15
    float s = 0.f;
    for (int i = seg; i < 512; i += 16) s += frac_part[i * 32 + col];
    acc[seg * 32 + col] = s;
    __syncthreads();
    if (t < 32) {
      float v = 0.f;
#pragma unroll
      for (int sg = 0; sg < 16; sg++) v += acc[sg * 32 + t];
      acc[t] = v;
    }
    __syncthreads();
    if (t == 0) {
      float loss = 0.f;
      for (int e = 0; e < 16; e++) {
        float ft = acc[e] * (1.f / 32768.f);
        float fp = acc[16 + e] * (1.f / 32768.f);
        loss += ft * fp;
      }
      out[8388608] = loss * 16.f;
    }
    return;
  }

  uint4* at    = (uint4*)smem;              // 2048 uint4 = 32 KB fragment order
  float* wtile = (float*)(smem + 32768);    // [e][tok] 16*64 fp32 = 4 KB

  int w = t >> 6, l = t & 63;   // w = col-block 0..7
  int r5 = l & 31, hi = l >> 5;

  // ---- A-stage: inputs fp32 -> bf16 -> fragment-order LDS ----
  // (row, j) -> uint4 idx (j>>1)*128 + (row>>5)*64 + (j&1)*32 + ((row&31)^(j>>1))
#pragma unroll
  for (int i = 0; i < 4; i++) {
    int idx = i * 512 + t;
    int row = idx >> 5;          // 0..63
    int j = idx & 31;
    const float4* src = (const float4*)(inputs + ((size_t)b * 64 + row) * 256 + j * 8);
    float4 f0 = src[0], f1 = src[1];
    unsigned int p0 = (unsigned int)f2bf(f0.x) | ((unsigned int)f2bf(f0.y) << 16);
    unsigned int p1 = (unsigned int)f2bf(f0.z) | ((unsigned int)f2bf(f0.w) << 16);
    unsigned int p2 = (unsigned int)f2bf(f1.x) | ((unsigned int)f2bf(f1.y) << 16);
    unsigned int p3 = (unsigned int)f2bf(f1.z) | ((unsigned int)f2bf(f1.w) << 16);
    int kb = j >> 1, hib = j & 1;
    at[kb * 128 + (row >> 5) * 64 + hib * 32 + ((row & 31) ^ kb)] =
        make_uint4(p0, p1, p2, p3);
  }
  // wtile transposed stage: combine[tok][e] -> wtile[e*64 + tok]
  {
    const float* cg = combine + (size_t)b * 1024;
#pragma unroll
    for (int i = 0; i < 2; i++) {
      int idx = i * 512 + t;
      wtile[(idx & 15) * 64 + (idx >> 4)] = cg[idx];
    }
  }

  // early B prefetch for (e=0, q=0)
  const uint4* wb = wpack + (size_t)w * 1024 + l;
  uint4 bregA[4], bregB[4];
  pref_b4(bregA, wb, 0);

  __syncthreads();   // LDS staging visible to all waves

  f32x16 facc[2];
#pragma unroll
  for (int mb = 0; mb < 2; mb++)
#pragma unroll
    for (int r = 0; r < 16; r++) facc[mb][r] = 0.f;
  f32x16 tacc[2];
  int rowoff = hi * 4;   // C/D layout row offset

  for (int e = 0; e < 17; e++) {
    const uint4* we = wb + (size_t)e * 8192;
    // zero-init tacc (inline-0 v_movs; no zc register block)
#pragma unroll
    for (int mb = 0; mb < 2; mb++)
#pragma unroll
      for (int r = 0; r < 16; r++) tacc[mb][r] = 0.f;

    pref_b4(bregB, we, 1);
    slot_mfma4(tacc, at, bregA, 0, hi, r5);
    pref_b4(bregA, we, 2);
    slot_mfma4(tacc, at, bregB, 1, hi, r5);
    pref_b4(bregB, we, 3);
    slot_mfma4(tacc, at, bregA, 2, hi, r5);
    if (e < 16) pref_b4(bregA, we + 8192, 0);
    slot_mfma4(tacc, at, bregB, 3, hi, r5);

    // scale-add full-K expert output: facc += w[row,e] * tacc (once per expert)
    if (e < 16) {
#pragma unroll
      for (int mb = 0; mb < 2; mb++)
#pragma unroll
        for (int rg = 0; rg < 4; rg++) {
          float4 w4 = *(const float4*)&wtile[e * 64 + mb * 32 + 8 * rg + rowoff];
          float wj[4] = {w4.x, w4.y, w4.z, w4.w};
#pragma unroll
          for (int j = 0; j < 4; j++)
            facc[mb][rg * 4 + j] += wj[j] * tacc[mb][rg * 4 + j];
        }
    } else {  // shared expert, weight 1.0
#pragma unroll
      for (int mb = 0; mb < 2; mb++)
#pragma unroll
        for (int r = 0; r < 16; r++) facc[mb][r] += tacc[mb][r];
    }
  }

  // ---- final epilogue: bias terms + store ----
  int col = w * 32 + r5;
  float sb = share_b[col];
  float eb[16];
#pragma unroll
  for (int e2 = 0; e2 < 16; e2++) eb[e2] = expert_b[e2 * 256 + col];
  // facc += sum_e w[row,e] * expert_b[e,col]
#pragma unroll
  for (int e2 = 0; e2 < 16; e2++)
#pragma unroll
    for (int mb = 0; mb < 2; mb++)
#pragma unroll
      for (int rg = 0; rg < 4; rg++) {
        float4 w4 = *(const float4*)&wtile[e2 * 64 + mb * 32 + 8 * rg + rowoff];
        float wj[4] = {w4.x, w4.y, w4.z, w4.w};
#pragma unroll
        for (int j = 0; j < 4; j++)
          facc[mb][rg * 4 + j] += wj[j] * eb[e2];
      }
#pragma unroll
  for (int mb = 0; mb < 2; mb++)
#pragma unroll
    for (int r = 0; r < 16; r++) {
      int row = mb * 32 + (r & 3) + ((r >> 2) << 3) + rowoff;
      out[((size_t)b * 64 + row) * 256 + col] = facc[mb][r] + sb;
    }
}

extern "C" void kernel_launch(void* const* d_in, const int* in_sizes, int n_in,
                              void* d_out, int out_size, void* d_ws, size_t ws_size,
                              hipStream_t stream) {
  const float* inputs   = (const float*)d_in[0];
  const float* conv_out = (const float*)d_in[1];
  const float* demb     = (const float*)d_in[2];
  const float* share_W  = (const float*)d_in[3];
  const float* share_b  = (const float*)d_in[4];
  const float* gate_W   = (const float*)d_in[5];
  const float* gate_b   = (const float*)d_in[6];
  const float* expert_W = (const float*)d_in[7];
  const float* expert_b = (const float*)d_in[8];
  const float* ln_g     = (const float*)d_in[9];
  const float* ln_b     = (const float*)d_in[10];
  float* out = (float*)d_out;
  char* ws = (char*)d_ws;

  uint4* wpack   = (uint4*)(ws);
  float* combine = (float*)(ws + 2228224);
  float* frac    = (float*)(ws + 4325376);

  // allow 36 KB dynamic LDS (idempotent; not a stream op, safe under capture)
  hipFuncSetAttribute((const void*)moe_gemm_kernel,
                      hipFuncAttributeMaxDynamicSharedMemorySize, 36864);

  prep_kernel<<<dim3(784), dim3(512), 0, stream>>>(
      conv_out, demb, gate_W, gate_b, ln_g, ln_b, share_W, expert_W,
      combine, frac, wpack);
  moe_gemm_kernel<<<dim3(513), dim3(512), 36864, stream>>>(
      inputs, wpack, combine, expert_b, share_b, out, frac);
}